// Round 3
// baseline (364.762 us; speedup 1.0000x reference)
//
#include <hip/hip_runtime.h>
#include <math.h>

#define DEVFN __global__ __launch_bounds__(256)

namespace {
constexpr int LL  = 128;   // L
constexpr int MM2 = 255;   // 2L-1
constexpr int NT  = 256;   // ntheta
constexpr int NP  = 512;   // nphi
constexpr int NC  = 32;    // C_IN
constexpr int NO  = 32;    // C_OUT
constexpr float TWO_PI = 6.283185307179586476925286766559f;
}

typedef short v8s __attribute__((ext_vector_type(8)));   // 8 bf16 (4 VGPRs)
typedef float v4f __attribute__((ext_vector_type(4)));   // 4 fp32 acc

__device__ inline unsigned short f2bf(float f) {
  unsigned int u = __float_as_uint(f);
  return (unsigned short)((u + 0x7FFFu + ((u >> 16) & 1u)) >> 16);  // RNE
}

// Balanced m-assignment for triangular-work kernels: XCD k owns
// m in {8k..8k+7} U {120-8k..127-8k} (work 128-m pairs to a constant sum).
__device__ inline int m_of(int k, int mloc) {
  return (mloc < 8) ? (8 * k + mloc) : (120 - 8 * k + (mloc - 8));
}

// ---------------------------------------------------------------- KP: prep (twiddles + x transpose)
DEVFN void kp_prep(const float* __restrict__ x, unsigned short* __restrict__ tw1t,
                   unsigned short* __restrict__ vt, unsigned short* __restrict__ xb) {
  __shared__ float sm[32][65];
  const int bid = blockIdx.x;
  const int tid = threadIdx.x;
  const float phi = TWO_PI / (float)NP;
  if (bid < 512) {
    const int idx = bid * 256 + tid;  // 0..131071
    const float fs = TWO_PI / (float)NP;
    {
      const int n = idx >> 9, p = idx & 511;
      const int m = n >> 1;
      const int k = (m * p) & (NP - 1);
      float s, c;
      sincosf(phi * (float)k, &s, &c);
      tw1t[idx] = f2bf((n & 1) ? (-s * fs) : (c * fs));
    }
    {
      const int p = idx >> 8, k = idx & 255;
      const int m = k >> 1;
      const int kk = (m * p) & (NP - 1);
      float s, c;
      sincosf(phi * (float)kk, &s, &c);
      vt[idx] = f2bf((k & 1) ? s : c);
    }
  } else {
    const int q = bid - 512;           // 0..2047
    const int t = q >> 3;
    const int p0 = (q & 7) * 64;
#pragma unroll
    for (int i = 0; i < 8; ++i) {
      const int idx = tid + i * 256;
      const int p = idx >> 5, c = idx & 31;
      sm[c][p] = x[((size_t)t * NP + p0 + p) * NC + c];
    }
    __syncthreads();
    const int c = tid >> 3, pg = tid & 7;
    unsigned short pk[8];
#pragma unroll
    for (int u = 0; u < 8; ++u) pk[u] = f2bf(sm[c][pg * 8 + u]);
    *(uint4*)(xb + ((size_t)(t * 32 + c)) * NP + p0 + pg * 8) = *(const uint4*)pk;
  }
}

// ---------------------------------------------------------------- K1: forward DFT via MFMA
// C[r][n] = sum_p Xb[r][p] * tw1t[n][p];  fw{r,i}[m][t][c] = C * wg[t]
// M=8192, N=256, K=512.  Tile BM=128 x BN=64 -> grid (64,4) = 256 blocks.
DEVFN void k1_mfma(const unsigned short* __restrict__ xb,
                   const unsigned short* __restrict__ tw1t,
                   const float* __restrict__ wg,
                   float* __restrict__ fwr, float* __restrict__ fwi) {
  __shared__ unsigned short As[128 * 32];
  __shared__ unsigned short Bs[64 * 32];
  const int tid = threadIdx.x;
  const int r0 = blockIdx.x * 128;
  const int n0 = blockIdx.y * 64;
  const int wid = tid >> 6, lane = tid & 63;
  const int wm = wid & 1, wn = wid >> 1;   // 2x2 waves, wave tile 64(M) x 32(N)
  v4f acc[4][2];
#pragma unroll
  for (int i = 0; i < 4; ++i)
#pragma unroll
    for (int j = 0; j < 2; ++j) {
      acc[i][j][0] = 0.f; acc[i][j][1] = 0.f; acc[i][j][2] = 0.f; acc[i][j][3] = 0.f;
    }
  const int lr = lane & 15, lk = (lane >> 4) * 8;
  for (int k0 = 0; k0 < 512; k0 += 32) {
#pragma unroll
    for (int s = 0; s < 3; ++s) {
      const int chunk = tid + s * 256;      // 768 chunks x 16B (A:512, B:256)
      if (chunk < 512) {
        const int row = chunk >> 2, c16 = chunk & 3;
        *(uint4*)&As[row * 32 + c16 * 8] =
            *(const uint4*)&xb[(size_t)(r0 + row) * 512 + k0 + c16 * 8];
      } else {
        const int bc = chunk - 512;
        const int row = bc >> 2, c16 = bc & 3;
        *(uint4*)&Bs[row * 32 + c16 * 8] =
            *(const uint4*)&tw1t[(size_t)(n0 + row) * 512 + k0 + c16 * 8];
      }
    }
    __syncthreads();
    v8s af[4], bf[2];
#pragma unroll
    for (int i = 0; i < 4; ++i) af[i] = *(const v8s*)&As[(wm * 64 + i * 16 + lr) * 32 + lk];
#pragma unroll
    for (int j = 0; j < 2; ++j) bf[j] = *(const v8s*)&Bs[(wn * 32 + j * 16 + lr) * 32 + lk];
#pragma unroll
    for (int i = 0; i < 4; ++i)
#pragma unroll
      for (int j = 0; j < 2; ++j)
        acc[i][j] = __builtin_amdgcn_mfma_f32_16x16x32_bf16(af[i], bf[j], acc[i][j], 0, 0, 0);
    __syncthreads();
  }
  const int lrow = (lane >> 4) * 4;
#pragma unroll
  for (int i = 0; i < 4; ++i) {
    const int rbase = r0 + wm * 64 + i * 16 + lrow;
    const int t = rbase >> 5, c0 = rbase & 31;
    const float w = wg[t];
#pragma unroll
    for (int j = 0; j < 2; ++j) {
      const int n = n0 + wn * 32 + j * 16 + lr;
      const int mI = n >> 1;
      float* dst = (n & 1) ? fwi : fwr;
      float4 v = {acc[i][j][0] * w, acc[i][j][1] * w, acc[i][j][2] * w, acc[i][j][3] * w};
      *(float4*)&dst[((size_t)mI * NT + t) * NC + c0] = v;
    }
  }
}

// ---------------------------------------------------------------- K2: flm (l >= m), 2 l per wave
// flm[m,l,c,s] = sum_t leg[l,m,t] * fw[m,t,c,s].  Lane = s*32+c.  fw is
// L2-resident per XCD (blockIdx.x = m -> XCD m%8 -> 16 m x 64 KB = 1 MB).
DEVFN void k2_flm(const float* __restrict__ leg, const float* __restrict__ fwr,
                  const float* __restrict__ fwi, float* __restrict__ flr,
                  float* __restrict__ fli) {
  const int m  = blockIdx.x;
  const int l0 = m + blockIdx.y * 8 + (threadIdx.x >> 6) * 2;
  if (l0 >= LL) return;
  const int lane = threadIdx.x & 63;
  const int c = lane & 31;
  const int l1 = min(l0 + 1, LL - 1);
  const float* fp = ((lane >> 5) ? fwi : fwr) + (size_t)m * NT * NC + c;
  const float* lgA = leg + ((size_t)(l0 * MM2 + 127 + m)) * NT;
  const float* lgB = leg + ((size_t)(l1 * MM2 + 127 + m)) * NT;
  float a0 = 0.f, a1 = 0.f;
#pragma unroll 4
  for (int t = 0; t < NT; t += 4) {
    const float f0 = fp[(t + 0) * NC];
    const float f1 = fp[(t + 1) * NC];
    const float f2 = fp[(t + 2) * NC];
    const float f3 = fp[(t + 3) * NC];
    const float4 bA = *(const float4*)(lgA + t);
    const float4 bB = *(const float4*)(lgB + t);
    a0 = fmaf(bA.x, f0, a0); a0 = fmaf(bA.y, f1, a0);
    a0 = fmaf(bA.z, f2, a0); a0 = fmaf(bA.w, f3, a0);
    a1 = fmaf(bB.x, f0, a1); a1 = fmaf(bB.y, f1, a1);
    a1 = fmaf(bB.z, f2, a1); a1 = fmaf(bB.w, f3, a1);
  }
  float* outp = (lane >> 5) ? fli : flr;
  outp[(size_t)(m * LL + l0) * NC + c] = a0;
  if (l0 + 1 < LL) outp[(size_t)(m * LL + l0 + 1) * NC + c] = a1;
}

// ---------------------------------------------------------------- K3: channel mix, wave per (m,l)
// Pure weight stream (132 MB read once).  Lane = c8*8 + o8: each lane owns
// a 4c x 4o tile, 16 coalesced float4 weight loads, shfl_xor reduce over c8.
DEVFN void k3_mix(const float* __restrict__ flr, const float* __restrict__ fli,
                  const float* __restrict__ wr, const float* __restrict__ wi,
                  float* __restrict__ ya, float* __restrict__ yb) {
  const int m  = blockIdx.x;
  const int wid = threadIdx.x >> 6, lane = threadIdx.x & 63;
  const int l = m + blockIdx.y * 4 + wid;
  if (l >= LL) return;
  const int c8 = lane >> 3;          // c-group: c = c8*4 + i
  const int o8 = lane & 7;           // o-quad:  o = o8*4 ..+3
  const int c0 = c8 * 4, o0 = o8 * 4;
  const float s0 = (m > 0) ? 1.0f : 0.0f;
  const size_t rp = ((size_t)(l * MM2 + 127 + m) * NC) * NO;
  const size_t rn = ((size_t)(l * MM2 + 127 - m) * NC) * NO;
  const float4 fa4 = *(const float4*)&flr[(size_t)(m * LL + l) * NC + c0];
  const float4 fb4 = *(const float4*)&fli[(size_t)(m * LL + l) * NC + c0];
  float4 accA = {0.f, 0.f, 0.f, 0.f}, accB = {0.f, 0.f, 0.f, 0.f};
#pragma unroll
  for (int i = 0; i < 4; ++i) {
    const int c = c0 + i;
    const float4 wrp = *(const float4*)&wr[rp + (size_t)c * NO + o0];
    const float4 wrn = *(const float4*)&wr[rn + (size_t)c * NO + o0];
    const float4 wip = *(const float4*)&wi[rp + (size_t)c * NO + o0];
    const float4 win = *(const float4*)&wi[rn + (size_t)c * NO + o0];
    const float fa = (i == 0) ? fa4.x : (i == 1) ? fa4.y : (i == 2) ? fa4.z : fa4.w;
    const float fb = (i == 0) ? fb4.x : (i == 1) ? fb4.y : (i == 2) ? fb4.z : fb4.w;
    float4 wa, wb;
    wa.x = fmaf(s0, wrn.x, wrp.x); wa.y = fmaf(s0, wrn.y, wrp.y);
    wa.z = fmaf(s0, wrn.z, wrp.z); wa.w = fmaf(s0, wrn.w, wrp.w);
    wb.x = fmaf(s0, win.x, -wip.x); wb.y = fmaf(s0, win.y, -wip.y);
    wb.z = fmaf(s0, win.z, -wip.z); wb.w = fmaf(s0, win.w, -wip.w);
    accA.x = fmaf(fa, wa.x, fmaf(fb, wb.x, accA.x));
    accA.y = fmaf(fa, wa.y, fmaf(fb, wb.y, accA.y));
    accA.z = fmaf(fa, wa.z, fmaf(fb, wb.z, accA.z));
    accA.w = fmaf(fa, wa.w, fmaf(fb, wb.w, accA.w));
    accB.x = fmaf(fa, wb.x, fmaf(-fb, wa.x, accB.x));
    accB.y = fmaf(fa, wb.y, fmaf(-fb, wa.y, accB.y));
    accB.z = fmaf(fa, wb.z, fmaf(-fb, wa.z, accB.z));
    accB.w = fmaf(fa, wb.w, fmaf(-fb, wa.w, accB.w));
  }
#pragma unroll
  for (int mask = 8; mask <= 32; mask <<= 1) {
    accA.x += __shfl_xor(accA.x, mask); accA.y += __shfl_xor(accA.y, mask);
    accA.z += __shfl_xor(accA.z, mask); accA.w += __shfl_xor(accA.w, mask);
    accB.x += __shfl_xor(accB.x, mask); accB.y += __shfl_xor(accB.y, mask);
    accB.z += __shfl_xor(accB.z, mask); accB.w += __shfl_xor(accB.w, mask);
  }
  if (c8 == 0) {
    *(float4*)&ya[(size_t)(m * LL + l) * NO + o0] = accA;
    *(float4*)&yb[(size_t)(m * LL + l) * NO + o0] = accB;
  }
}

// ---------------------------------------------------------------- K4: inverse Legendre -> Ut bf16
// Ut[r=(t*32+o)][k] : k=2m -> cos coeff, k=2m+1 -> sin coeff.  Balanced XCD swizzle.
DEVFN void k4_G(const float* __restrict__ leg, const float* __restrict__ ya,
                const float* __restrict__ yb, unsigned short* __restrict__ ut) {
  const int fid = blockIdx.x + (int)blockIdx.y * 128;   // grid (128,8) -> 0..1023
  const int xk  = fid & 7;
  const int loc = fid >> 3;          // 0..127
  const int m   = m_of(xk, loc >> 3);
  const int tc  = loc & 7;
  const int o = threadIdx.x & 31;
  const int tq = threadIdx.x >> 5;
  const int t0 = tc * 32 + tq * 4;
  float aa[4] = {}, bb[4] = {};
#pragma unroll 4
  for (int l = m; l < LL; ++l) {
    const float4 g = *(const float4*)(leg + ((size_t)(l * MM2 + 127 + m)) * NT + t0);
    const float yav = ya[(m * LL + l) * NO + o];
    const float ybv = yb[(m * LL + l) * NO + o];
    aa[0] = fmaf(g.x, yav, aa[0]);  bb[0] = fmaf(g.x, ybv, bb[0]);
    aa[1] = fmaf(g.y, yav, aa[1]);  bb[1] = fmaf(g.y, ybv, bb[1]);
    aa[2] = fmaf(g.z, yav, aa[2]);  bb[2] = fmaf(g.z, ybv, bb[2]);
    aa[3] = fmaf(g.w, yav, aa[3]);  bb[3] = fmaf(g.w, ybv, bb[3]);
  }
#pragma unroll
  for (int i = 0; i < 4; ++i) {
    const unsigned int pk = (unsigned int)f2bf(aa[i]) | ((unsigned int)f2bf(bb[i]) << 16);
    *(unsigned int*)&ut[((size_t)((t0 + i) * 32 + o)) * 256 + 2 * m] = pk;
  }
}

// ---------------------------------------------------------------- K5: inverse DFT via MFMA (A=vt)
// D[p][r] = sum_k vt[p][k] * ut[r][k];  out[o][t][p] = D,  r=t*32+o   (M=512,N=8192,K=256)
DEVFN void k5_mfma(const unsigned short* __restrict__ ut,
                   const unsigned short* __restrict__ vt,
                   float* __restrict__ out) {
  __shared__ unsigned short As[128 * 32];  // vt tile (p rows)
  __shared__ unsigned short Bs[128 * 32];  // ut tile (r rows)
  const int tid = threadIdx.x;
  const int p0 = blockIdx.x * 128;
  const int r0 = blockIdx.y * 128;
  const int wid = tid >> 6, lane = tid & 63;
  const int wm = wid & 1, wn = wid >> 1;
  v4f acc[4][4];
#pragma unroll
  for (int i = 0; i < 4; ++i)
#pragma unroll
    for (int j = 0; j < 4; ++j) {
      acc[i][j][0] = 0.f; acc[i][j][1] = 0.f; acc[i][j][2] = 0.f; acc[i][j][3] = 0.f;
    }
  const int lr = lane & 15, lk = (lane >> 4) * 8;
  for (int k0 = 0; k0 < 256; k0 += 32) {
#pragma unroll
    for (int s = 0; s < 2; ++s) {
      const int chunk = tid + s * 256;
      const int row = chunk >> 2, c16 = chunk & 3;
      *(uint4*)&As[row * 32 + c16 * 8] =
          *(const uint4*)&vt[(size_t)(p0 + row) * 256 + k0 + c16 * 8];
      *(uint4*)&Bs[row * 32 + c16 * 8] =
          *(const uint4*)&ut[(size_t)(r0 + row) * 256 + k0 + c16 * 8];
    }
    __syncthreads();
    v8s af[4], bf[4];
#pragma unroll
    for (int i = 0; i < 4; ++i) af[i] = *(const v8s*)&As[(wm * 64 + i * 16 + lr) * 32 + lk];
#pragma unroll
    for (int j = 0; j < 4; ++j) bf[j] = *(const v8s*)&Bs[(wn * 64 + j * 16 + lr) * 32 + lk];
#pragma unroll
    for (int i = 0; i < 4; ++i)
#pragma unroll
      for (int j = 0; j < 4; ++j)
        acc[i][j] = __builtin_amdgcn_mfma_f32_16x16x32_bf16(af[i], bf[j], acc[i][j], 0, 0, 0);
    __syncthreads();
  }
  const int lrow = (lane >> 4) * 4;
#pragma unroll
  for (int i = 0; i < 4; ++i) {
    const int pbase = p0 + wm * 64 + i * 16 + lrow;
#pragma unroll
    for (int j = 0; j < 4; ++j) {
      const int r = r0 + wn * 64 + j * 16 + lr;
      const int t = r >> 5, o = r & 31;
      float4 v = {acc[i][j][0], acc[i][j][1], acc[i][j][2], acc[i][j][3]};
      *(float4*)&out[((size_t)o * NT + t) * NP + pbase] = v;
    }
  }
}

// ---------------------------------------------------------------- launch
extern "C" void kernel_launch(void* const* d_in, const int* in_sizes, int n_in,
                              void* d_out, int out_size, void* d_ws, size_t ws_size,
                              hipStream_t stream) {
  const float* x   = (const float*)d_in[0];
  const float* wr  = (const float*)d_in[1];
  const float* wi  = (const float*)d_in[2];
  const float* leg = (const float*)d_in[3];
  const float* wg  = (const float*)d_in[4];
  float* out = (float*)d_out;

  unsigned short* tw1t = (unsigned short*)d_ws;     // 256*512   = 131072
  unsigned short* vt   = tw1t + 131072;             // 512*256   = 131072
  unsigned short* xb   = vt + 131072;               // 8192*512  = 4194304
  unsigned short* ut   = xb + 4194304;              // 8192*256  = 2097152
  float* fwr = (float*)(ut + 2097152);              // 128*256*32 = 1048576
  float* fwi = fwr + 1048576;
  float* flr = fwi + 1048576;                       // 128*128*32 = 524288
  float* fli = flr + 524288;
  float* ya  = fli + 524288;
  float* yb  = ya + 524288;                         // total ~26 MB

  hipLaunchKernelGGL(kp_prep, dim3(2560), dim3(256), 0, stream, x, tw1t, vt, xb);
  hipLaunchKernelGGL(k1_mfma, dim3(64, 4), dim3(256), 0, stream, xb, tw1t, wg, fwr, fwi);
  hipLaunchKernelGGL(k2_flm, dim3(128, 16), dim3(256), 0, stream, leg, fwr, fwi, flr, fli);
  hipLaunchKernelGGL(k3_mix, dim3(128, 32), dim3(256), 0, stream, flr, fli, wr, wi, ya, yb);
  hipLaunchKernelGGL(k4_G, dim3(128, 8), dim3(256), 0, stream, leg, ya, yb, ut);
  hipLaunchKernelGGL(k5_mfma, dim3(4, 64), dim3(256), 0, stream, ut, vt, out);
}